// Round 6
// baseline (228.176 us; speedup 1.0000x reference)
//
#include <hip/hip_runtime.h>
#include <hip/hip_bf16.h>

#define NB 32
#define NN 2048
#define DD 64
#define NCH 32
#define LOG2E 1.44269504088896340736f

typedef __attribute__((ext_vector_type(8))) short short8;
typedef __attribute__((ext_vector_type(4))) short short4v;
typedef __attribute__((ext_vector_type(4))) float f32x4;

// v_mfma_f32_16x16x16_bf16 (A/B = 4 bf16).
#define MFMA16(A, B, C) \
  __builtin_amdgcn_mfma_f32_16x16x16bf16_1k((A), (B), (C), 0, 0, 0)

#define GLOAD_LDS16(gp, lp)                                                   \
  __builtin_amdgcn_global_load_lds(                                          \
      (const __attribute__((address_space(1))) void*)(gp),                   \
      (__attribute__((address_space(3))) void*)(lp), 16, 0, 0)

__device__ __forceinline__ short f2bf(float x) {
  __bf16 h = (__bf16)x;
  return __builtin_bit_cast(short, h);
}

__device__ __forceinline__ float fast_exp2(float x) {
#if __has_builtin(__builtin_amdgcn_exp2f)
  return __builtin_amdgcn_exp2f(x);
#else
  return exp2f(x);
#endif
}

// ---------- prep 1: x fp32 -> xbf (row-major bf16) + xT (per-batch [D][N] bf16)
__global__ __launch_bounds__(256) void prep_x(const float* __restrict__ x,
                                              short* __restrict__ xbf,
                                              short* __restrict__ xT) {
  __shared__ short t[64 * 72];
  const int tid = threadIdx.x;
  const int n0 = blockIdx.x * 64;
  const int b = blockIdx.y;
  const int r = tid >> 2;
  const int cg = tid & 3;

  const float* src = x + ((size_t)b * NN + n0 + r) * DD + cg * 16;
  short8 v[2];
#pragma unroll
  for (int h = 0; h < 2; ++h) {
    float4 f0 = ((const float4*)src)[h * 2];
    float4 f1 = ((const float4*)src)[h * 2 + 1];
    short8 a;
    a[0] = f2bf(f0.x); a[1] = f2bf(f0.y); a[2] = f2bf(f0.z); a[3] = f2bf(f0.w);
    a[4] = f2bf(f1.x); a[5] = f2bf(f1.y); a[6] = f2bf(f1.z); a[7] = f2bf(f1.w);
    v[h] = a;
  }
  short* dst = xbf + ((size_t)b * NN + n0 + r) * DD + cg * 16;
  ((short8*)dst)[0] = v[0];
  ((short8*)dst)[1] = v[1];
  *(short8*)&t[r * 72 + cg * 16] = v[0];
  *(short8*)&t[r * 72 + cg * 16 + 8] = v[1];
  __syncthreads();
  short8 o0, o1;
#pragma unroll
  for (int i = 0; i < 8; ++i) o0[i] = t[(cg * 16 + i) * 72 + r];
#pragma unroll
  for (int i = 0; i < 8; ++i) o1[i] = t[(cg * 16 + 8 + i) * 72 + r];
  short* dstT = xT + ((size_t)b * DD + r) * NN + n0 + cg * 16;
  ((short8*)dstT)[0] = o0;
  ((short8*)dstT)[1] = o1;
}

// ---------- prep 2: adj int32 -> bitmask
__global__ __launch_bounds__(256) void prep_adj(const int* __restrict__ adj,
                                                unsigned long long* __restrict__ bits) {
  const int i = blockIdx.x * 256 + threadIdx.x;
  unsigned long long m = __ballot(adj[i] > 0);
  if ((threadIdx.x & 63) == 0) bits[i >> 6] = m;
}

// ---------- main: 4 waves x 16 q-rows = 64 q-rows/block; 1024 blocks
// (4 blocks/CU, 4 waves/SIMD). K-frags from global (L1-hot), V^T staged in
// LDS (DMA, swizzled), P register-only, l-sum via ones-MFMA.
__global__ __launch_bounds__(256, 4) void gat_flash5(
    const float* __restrict__ x, const short* __restrict__ xbf,
    const short* __restrict__ xT, const unsigned long long* __restrict__ adjb,
    float* __restrict__ out) {
  __shared__ short sV[2][64 * 64];  // [d][key], swizzled 16B blocks

  const int tid = threadIdx.x;
  const int w = tid >> 6;          // 0..3
  const int l = tid & 63;
  const int lane16 = l & 15;
  const int quad = l >> 4;
  const int b = blockIdx.y;
  const int qbase = blockIdx.x * 64;

  const short* xb_b = xbf + (size_t)b * NN * DD;
  const short* xT_b = xT + (size_t)b * DD * NN;

  // V staging geometry: group g = w*2+i covers d-rows g*8..g*8+7
  const int st_row = (l >> 3);
  const int st_j = (l & 7) ^ (l >> 3);

  // ---- Q B-frags (n=lane16=q, k=d), pre-scaled by (1/8)*log2e ----
  const float qs = 0.125f * LOG2E;
  const float* qp = x + ((size_t)b * NN + qbase + w * 16 + lane16) * DD;
  short8 qf[2];
#pragma unroll
  for (int ks = 0; ks < 2; ++ks) {
    float4 v0 = *(const float4*)(qp + ks * 32 + quad * 8);
    float4 v1 = *(const float4*)(qp + ks * 32 + quad * 8 + 4);
    short8 a;
    a[0] = f2bf(v0.x * qs); a[1] = f2bf(v0.y * qs);
    a[2] = f2bf(v0.z * qs); a[3] = f2bf(v0.w * qs);
    a[4] = f2bf(v1.x * qs); a[5] = f2bf(v1.y * qs);
    a[6] = f2bf(v1.z * qs); a[7] = f2bf(v1.w * qs);
    qf[ks] = a;
  }

  f32x4 acc[4];   // [dt] O^T tiles: row=d=quad*4+reg, col=q=lane16
  f32x4 acc_l = {0.f, 0.f, 0.f, 0.f};
#pragma unroll
  for (int dt = 0; dt < 4; ++dt) acc[dt] = {0.f, 0.f, 0.f, 0.f};

  short4v ones;
  ones[0] = 0x3F80; ones[1] = 0x3F80; ones[2] = 0x3F80; ones[3] = 0x3F80;

  const unsigned long long* adjrow =
      adjb + (size_t)(qbase + w * 16 + lane16) * (NN / 64);

  // ---- stage chunk 0 V^T into buf 0 (wave w: 2 KB) ----
#pragma unroll
  for (int i = 0; i < 2; ++i) {
    const int g = w * 2 + i;
    GLOAD_LDS16(xT_b + (size_t)(g * 8 + st_row) * NN + st_j * 8,
                &sV[0][g * 512]);
  }
  __syncthreads();

  for (int c = 0; c < NCH; ++c) {
    const int cur = c & 1;
    const int kb = c * 64;
    if (c + 1 < NCH) {
      const int kb2 = kb + 64;
#pragma unroll
      for (int i = 0; i < 2; ++i) {
        const int g = w * 2 + i;
        GLOAD_LDS16(xT_b + (size_t)(g * 8 + st_row) * NN + kb2 + st_j * 8,
                    &sV[cur ^ 1][g * 512]);
      }
    }

    // adjacency bits for this wave's 16 q-rows x 64 keys
    unsigned long long a = adjrow[c] >> (quad * 4);
    const unsigned wlo = (unsigned)a;
    const unsigned whi = (unsigned)(a >> 32);

    const short* sVc = sV[cur];

#pragma unroll
    for (int nt = 0; nt < 4; ++nt) {
      // S^T tile: D[m=key][n=q]; K A-frags straight from global (L1-hot)
      f32x4 s = {0.f, 0.f, 0.f, 0.f};
#pragma unroll
      for (int ks = 0; ks < 2; ++ks) {
        short8 kf = *(const short8*)&xb_b[(size_t)(kb + nt * 16 + lane16) * DD +
                                          ks * 32 + quad * 8];
        s = __builtin_amdgcn_mfma_f32_16x16x32_bf16(kf, qf[ks], s, 0, 0, 0);
      }

      // exp2 (trans pipe) then mask-to-zero -> P^T in registers
      const unsigned wb = (nt < 2) ? wlo : whi;
      short4v pf;
#pragma unroll
      for (int r = 0; r < 4; ++r) {
        const unsigned bit = (wb >> ((nt & 1) * 16 + r)) & 1u;
        float e = fast_exp2(s[r]);
        float p = bit ? e : 0.f;
        pf[r] = f2bf(p);
      }

      // l += ones * P^T
      acc_l = MFMA16(ones, pf, acc_l);

      // O^T += V^T P^T  (A = V^T frag from LDS, B = pf from registers)
#pragma unroll
      for (int dt = 0; dt < 4; ++dt) {
        const int jb2 = (nt * 2 + (quad >> 1)) ^ (lane16 & 7);
        short4v vf = *(const short4v*)&sVc[(dt * 16 + lane16) * 64 + jb2 * 8 +
                                           (quad & 1) * 4];
        acc[dt] = MFMA16(vf, pf, acc[dt]);
      }
    }
    __syncthreads();  // buf[cur] consumed; next iter overwrites it
  }

  // ---- epilogue: every lane holds l[q=lane16] in acc_l[0] ----
  const float inv = 1.0f / acc_l[0];
  float* op = out + ((size_t)b * NN + qbase + w * 16 + lane16) * DD + quad * 4;
#pragma unroll
  for (int dt = 0; dt < 4; ++dt) {
    float4 o;
    o.x = acc[dt][0] * inv;
    o.y = acc[dt][1] * inv;
    o.z = acc[dt][2] * inv;
    o.w = acc[dt][3] * inv;
    *(float4*)(op + dt * 16) = o;
  }
}

extern "C" void kernel_launch(void* const* d_in, const int* in_sizes, int n_in,
                              void* d_out, int out_size, void* d_ws,
                              size_t ws_size, hipStream_t stream) {
  const float* x = (const float*)d_in[0];
  const int* adj = (const int*)d_in[1];
  float* out = (float*)d_out;

  short* xbf = (short*)d_ws;                             // 8 MB
  short* xT = xbf + (size_t)NB * NN * DD;                // 8 MB
  unsigned long long* adjb =
      (unsigned long long*)(xT + (size_t)NB * NN * DD);  // 512 KB

  prep_x<<<dim3(NN / 64, NB), 256, 0, stream>>>(x, xbf, xT);
  prep_adj<<<(NN * NN) / 256, 256, 0, stream>>>(adj, adjb);
  gat_flash5<<<dim3(NN / 64, NB), 256, 0, stream>>>(x, xbf, xT, adjb, out);
}

// Round 7
// 149.022 us; speedup vs baseline: 1.5312x; 1.5312x over previous
//
#include <hip/hip_runtime.h>
#include <hip/hip_bf16.h>

#define NB 32
#define NN 2048
#define DD 64
#define NCH 32
#define LOG2E 1.44269504088896340736f

typedef __attribute__((ext_vector_type(8))) short short8;
typedef __attribute__((ext_vector_type(4))) short short4v;
typedef __attribute__((ext_vector_type(4))) float f32x4;

#define MFMA32K(A, B, C) \
  __builtin_amdgcn_mfma_f32_16x16x32_bf16((A), (B), (C), 0, 0, 0)
#define MFMA16(A, B, C) \
  __builtin_amdgcn_mfma_f32_16x16x16bf16_1k((A), (B), (C), 0, 0, 0)

#define GLOAD_LDS16(gp, lp)                                                   \
  __builtin_amdgcn_global_load_lds(                                          \
      (const __attribute__((address_space(1))) void*)(gp),                   \
      (__attribute__((address_space(3))) void*)(lp), 16, 0, 0)

__device__ __forceinline__ short f2bf(float x) {
  __bf16 h = (__bf16)x;
  return __builtin_bit_cast(short, h);
}

__device__ __forceinline__ float fast_exp2(float x) {
#if __has_builtin(__builtin_amdgcn_exp2f)
  return __builtin_amdgcn_exp2f(x);
#else
  return exp2f(x);
#endif
}

// ---------- prep: build fragment-major bf16 image of x.
// IMG[b][c] = 16 units x 64 lanes x 16B (16 KB per chunk):
//   unit u<8  (nt=u>>1, ks=u&1):  lane l gets K[c*64+nt*16+(l&15)][ks*32+(l>>4)*8 + 0..7]
//   unit u>=8 (dt=(u-8)>>1, ntp=(u-8)&1): lane l gets, for h=0,1:
//       V^T[dt*16+(l&15)][c*64 + (2*ntp+h)*16 + (l>>4)*4 + 0..3]
// LDS image after global_load_lds == global image, and every fragment read in
// the main kernel is addr = unit_base + lane*16B -> conflict-free.
__global__ __launch_bounds__(256) void prep_img(const float* __restrict__ x,
                                                short* __restrict__ img) {
  __shared__ short t[64 * 72];
  const int tid = threadIdx.x;
  const int c = blockIdx.x;
  const int b = blockIdx.y;
  const int r = tid >> 2;
  const int cg = tid & 3;

  const float* src = x + ((size_t)b * NN + c * 64 + r) * DD + cg * 16;
#pragma unroll
  for (int h = 0; h < 2; ++h) {
    float4 f0 = ((const float4*)src)[h * 2];
    float4 f1 = ((const float4*)src)[h * 2 + 1];
    short8 a;
    a[0] = f2bf(f0.x); a[1] = f2bf(f0.y); a[2] = f2bf(f0.z); a[3] = f2bf(f0.w);
    a[4] = f2bf(f1.x); a[5] = f2bf(f1.y); a[6] = f2bf(f1.z); a[7] = f2bf(f1.w);
    *(short8*)&t[r * 72 + cg * 16 + h * 8] = a;
  }
  __syncthreads();

  short* imgc = img + (size_t)(b * NCH + c) * 16 * 512;

  // K units: row-major b128 pulls from the padded LDS tile
#pragma unroll
  for (int i = 0; i < 2; ++i) {
    const int kc = tid + i * 256;
    const int u = kc >> 6, l = kc & 63;
    const int nt = u >> 1, ks = u & 1;
    short8 v = *(const short8*)&t[(nt * 16 + (l & 15)) * 72 + ks * 32 +
                                  (l >> 4) * 8];
    *(short8*)&imgc[(size_t)u * 512 + l * 8] = v;
  }
  // V units: transposed gather (scalar LDS reads), paired nt tiles per 16B
#pragma unroll
  for (int i = 0; i < 2; ++i) {
    const int vc = tid + i * 256;
    const int u = vc >> 6, l = vc & 63;
    const int dt = u >> 1, ntp = u & 1;
    const int d = dt * 16 + (l & 15);
    const int k0 = ntp * 32 + ((l >> 4) << 2);
    short8 o;
#pragma unroll
    for (int h = 0; h < 2; ++h)
#pragma unroll
      for (int r2 = 0; r2 < 4; ++r2)
        o[h * 4 + r2] = t[(k0 + h * 16 + r2) * 72 + d];
    *(short8*)&imgc[(size_t)(8 + u) * 512 + l * 8] = o;
  }
}

// ---------- prep 2: adj int32 -> bitmask
__global__ __launch_bounds__(256) void prep_adj(const int* __restrict__ adj,
                                                unsigned long long* __restrict__ bits) {
  const int i = blockIdx.x * 256 + threadIdx.x;
  unsigned long long m = __ballot(adj[i] > 0);
  if ((threadIdx.x & 63) == 0) bits[i >> 6] = m;
}

// ---------- main: 4 waves x 32 q-rows = 128 q-rows/block; grid (16,32)=512
// blocks -> 2 independent blocks/CU. Fragment-major LDS images (zero bank
// conflicts), S^T formulation, register-only P, l-sum via ones-MFMA.
__global__ __launch_bounds__(256, 2) void gat_flash6(
    const float* __restrict__ x, const short* __restrict__ img,
    const unsigned long long* __restrict__ adjb, float* __restrict__ out) {
  __shared__ short sI[2][8192];  // [buf][unit*512 + lane*8]; K units 0-7, V 8-15

  const int tid = threadIdx.x;
  const int w = tid >> 6;
  const int l = tid & 63;
  const int lane16 = l & 15;
  const int quad = l >> 4;
  const int b = blockIdx.y;
  const int qbase = blockIdx.x * 128 + w * 32;

  // ---- Q B-frags (n=lane16=q, k=quad*8+j=d), pre-scaled by (1/8)*log2e ----
  const float qs = 0.125f * LOG2E;
  short8 qf[2][2];
#pragma unroll
  for (int qt = 0; qt < 2; ++qt) {
    const float* qp = x + ((size_t)b * NN + qbase + qt * 16 + lane16) * DD;
#pragma unroll
    for (int ks = 0; ks < 2; ++ks) {
      float4 v0 = *(const float4*)(qp + ks * 32 + quad * 8);
      float4 v1 = *(const float4*)(qp + ks * 32 + quad * 8 + 4);
      short8 a;
      a[0] = f2bf(v0.x * qs); a[1] = f2bf(v0.y * qs);
      a[2] = f2bf(v0.z * qs); a[3] = f2bf(v0.w * qs);
      a[4] = f2bf(v1.x * qs); a[5] = f2bf(v1.y * qs);
      a[6] = f2bf(v1.z * qs); a[7] = f2bf(v1.w * qs);
      qf[qt][ks] = a;
    }
  }

  f32x4 acc[2][4];  // [qt][dt]: row=d=quad*4+reg, col=q=lane16
  f32x4 acc_l[2];
#pragma unroll
  for (int qt = 0; qt < 2; ++qt) {
    acc_l[qt] = {0.f, 0.f, 0.f, 0.f};
#pragma unroll
    for (int dt = 0; dt < 4; ++dt) acc[qt][dt] = {0.f, 0.f, 0.f, 0.f};
  }
  short4v ones;
  ones[0] = 0x3F80; ones[1] = 0x3F80; ones[2] = 0x3F80; ones[3] = 0x3F80;

  const short* img_b = img + (size_t)b * NCH * 16 * 512;
  const unsigned long long* ar0 = adjb + (size_t)(qbase + lane16) * NCH;
  const unsigned long long* ar1 = adjb + (size_t)(qbase + 16 + lane16) * NCH;

  // stage chunk 0 (wave w handles units w, w+4, w+8, w+12)
#pragma unroll
  for (int i = 0; i < 4; ++i) {
    const int u = i * 4 + w;
    GLOAD_LDS16(img_b + (size_t)u * 512 + l * 8, &sI[0][u * 512]);
  }
  __syncthreads();

  for (int c = 0; c < NCH; ++c) {
    const int cur = c & 1;
    if (c + 1 < NCH) {
#pragma unroll
      for (int i = 0; i < 4; ++i) {
        const int u = i * 4 + w;
        GLOAD_LDS16(img_b + ((size_t)(c + 1) * 16 + u) * 512 + l * 8,
                    &sI[cur ^ 1][u * 512]);
      }
    }

    const unsigned long long a0 = ar0[c] >> (quad * 4);
    const unsigned long long a1 = ar1[c] >> (quad * 4);
    const unsigned lo0 = (unsigned)a0, hi0 = (unsigned)(a0 >> 32);
    const unsigned lo1 = (unsigned)a1, hi1 = (unsigned)(a1 >> 32);

    const short* sK = sI[cur];
    const short* sV = sI[cur] + 4096;

#pragma unroll
    for (int ntp = 0; ntp < 2; ++ntp) {
      short4v pf[2][2];  // [h][qt]
#pragma unroll
      for (int h = 0; h < 2; ++h) {
        const int nt = ntp * 2 + h;
        f32x4 s0 = {0.f, 0.f, 0.f, 0.f};
        f32x4 s1 = {0.f, 0.f, 0.f, 0.f};
#pragma unroll
        for (int ks = 0; ks < 2; ++ks) {
          short8 kf = *(const short8*)&sK[(nt * 2 + ks) * 512 + l * 8];
          s0 = MFMA32K(kf, qf[0][ks], s0);
          s1 = MFMA32K(kf, qf[1][ks], s1);
        }
        const unsigned w0 = (nt < 2) ? lo0 : hi0;
        const unsigned w1 = (nt < 2) ? lo1 : hi1;
        const int sh = (nt & 1) * 16;
#pragma unroll
        for (int r = 0; r < 4; ++r) {
          float e0 = fast_exp2(s0[r]);
          float e1 = fast_exp2(s1[r]);
          float p0 = ((w0 >> (sh + r)) & 1u) ? e0 : 0.f;
          float p1 = ((w1 >> (sh + r)) & 1u) ? e1 : 0.f;
          pf[h][0][r] = f2bf(p0);
          pf[h][1][r] = f2bf(p1);
        }
        acc_l[0] = MFMA16(ones, pf[h][0], acc_l[0]);
        acc_l[1] = MFMA16(ones, pf[h][1], acc_l[1]);
      }
      // PV: one b128 per (dt, ntp) covers both nt tiles of the pair
#pragma unroll
      for (int dt = 0; dt < 4; ++dt) {
        short8 vv = *(const short8*)&sV[(dt * 2 + ntp) * 512 + l * 8];
        short4v vlo, vhi;
        vlo[0] = vv[0]; vlo[1] = vv[1]; vlo[2] = vv[2]; vlo[3] = vv[3];
        vhi[0] = vv[4]; vhi[1] = vv[5]; vhi[2] = vv[6]; vhi[3] = vv[7];
        acc[0][dt] = MFMA16(vlo, pf[0][0], acc[0][dt]);
        acc[1][dt] = MFMA16(vlo, pf[0][1], acc[1][dt]);
        acc[0][dt] = MFMA16(vhi, pf[1][0], acc[0][dt]);
        acc[1][dt] = MFMA16(vhi, pf[1][1], acc[1][dt]);
      }
    }
    __syncthreads();
  }

  // ---- epilogue: lane holds l[q=lane16] in acc_l[qt][0] ----
#pragma unroll
  for (int qt = 0; qt < 2; ++qt) {
    const float inv = 1.0f / acc_l[qt][0];
    float* op =
        out + ((size_t)b * NN + qbase + qt * 16 + lane16) * DD + quad * 4;
#pragma unroll
    for (int dt = 0; dt < 4; ++dt) {
      float4 o;
      o.x = acc[qt][dt][0] * inv;
      o.y = acc[qt][dt][1] * inv;
      o.z = acc[qt][dt][2] * inv;
      o.w = acc[qt][dt][3] * inv;
      *(float4*)(op + dt * 16) = o;
    }
  }
}

extern "C" void kernel_launch(void* const* d_in, const int* in_sizes, int n_in,
                              void* d_out, int out_size, void* d_ws,
                              size_t ws_size, hipStream_t stream) {
  const float* x = (const float*)d_in[0];
  const int* adj = (const int*)d_in[1];
  float* out = (float*)d_out;

  short* img = (short*)d_ws;  // 32 b x 32 c x 16 units x 512 shorts = 16 MB
  unsigned long long* adjb =
      (unsigned long long*)(img + (size_t)NB * NCH * 16 * 512);  // 512 KB

  prep_img<<<dim3(NCH, NB), 256, 0, stream>>>(x, img);
  prep_adj<<<(NN * NN) / 256, 256, 0, stream>>>(adj, adjb);
  gat_flash6<<<dim3(NN / 128, NB), 256, 0, stream>>>(x, img, adjb, out);
}

// Round 8
// 147.353 us; speedup vs baseline: 1.5485x; 1.0113x over previous
//
#include <hip/hip_runtime.h>
#include <hip/hip_bf16.h>

#define NB 32
#define NN 2048
#define DD 64
#define NCH 32
#define LOG2E 1.44269504088896340736f

typedef __attribute__((ext_vector_type(8))) short short8;
typedef __attribute__((ext_vector_type(4))) short short4v;
typedef __attribute__((ext_vector_type(4))) float f32x4;

#define MFMA32K(A, B, C) \
  __builtin_amdgcn_mfma_f32_16x16x32_bf16((A), (B), (C), 0, 0, 0)
#define MFMA16(A, B, C) \
  __builtin_amdgcn_mfma_f32_16x16x16bf16_1k((A), (B), (C), 0, 0, 0)

#define GLOAD_LDS16(gp, lp)                                                   \
  __builtin_amdgcn_global_load_lds(                                          \
      (const __attribute__((address_space(1))) void*)(gp),                   \
      (__attribute__((address_space(3))) void*)(lp), 16, 0, 0)

__device__ __forceinline__ short f2bf(float x) {
  __bf16 h = (__bf16)x;
  return __builtin_bit_cast(short, h);
}

__device__ __forceinline__ float fast_exp2(float x) {
#if __has_builtin(__builtin_amdgcn_exp2f)
  return __builtin_amdgcn_exp2f(x);
#else
  return exp2f(x);
#endif
}

// ---------- prep: fragment-major bf16 image of x (unchanged from round 7).
__global__ __launch_bounds__(256) void prep_img(const float* __restrict__ x,
                                                short* __restrict__ img) {
  __shared__ short t[64 * 72];
  const int tid = threadIdx.x;
  const int c = blockIdx.x;
  const int b = blockIdx.y;
  const int r = tid >> 2;
  const int cg = tid & 3;

  const float* src = x + ((size_t)b * NN + c * 64 + r) * DD + cg * 16;
#pragma unroll
  for (int h = 0; h < 2; ++h) {
    float4 f0 = ((const float4*)src)[h * 2];
    float4 f1 = ((const float4*)src)[h * 2 + 1];
    short8 a;
    a[0] = f2bf(f0.x); a[1] = f2bf(f0.y); a[2] = f2bf(f0.z); a[3] = f2bf(f0.w);
    a[4] = f2bf(f1.x); a[5] = f2bf(f1.y); a[6] = f2bf(f1.z); a[7] = f2bf(f1.w);
    *(short8*)&t[r * 72 + cg * 16 + h * 8] = a;
  }
  __syncthreads();

  short* imgc = img + (size_t)(b * NCH + c) * 16 * 512;

#pragma unroll
  for (int i = 0; i < 2; ++i) {
    const int kc = tid + i * 256;
    const int u = kc >> 6, l = kc & 63;
    const int nt = u >> 1, ks = u & 1;
    short8 v = *(const short8*)&t[(nt * 16 + (l & 15)) * 72 + ks * 32 +
                                  (l >> 4) * 8];
    *(short8*)&imgc[(size_t)u * 512 + l * 8] = v;
  }
#pragma unroll
  for (int i = 0; i < 2; ++i) {
    const int vc = tid + i * 256;
    const int u = vc >> 6, l = vc & 63;
    const int dt = u >> 1, ntp = u & 1;
    const int d = dt * 16 + (l & 15);
    const int k0 = ntp * 32 + ((l >> 4) << 2);
    short8 o;
#pragma unroll
    for (int h = 0; h < 2; ++h)
#pragma unroll
      for (int r2 = 0; r2 < 4; ++r2)
        o[h * 4 + r2] = t[(k0 + h * 16 + r2) * 72 + d];
    *(short8*)&imgc[(size_t)(8 + u) * 512 + l * 8] = o;
  }
}

// ---------- prep 2: adj int32 -> bitmask
__global__ __launch_bounds__(256) void prep_adj(const int* __restrict__ adj,
                                                unsigned long long* __restrict__ bits) {
  const int i = blockIdx.x * 256 + threadIdx.x;
  unsigned long long m = __ballot(adj[i] > 0);
  if ((threadIdx.x & 63) == 0) bits[i >> 6] = m;
}

// one chunk's compute: S^T via MFMA32K, masked exp2, PV via paired MFMA16.
__device__ __forceinline__ void chunk_body(
    const short* __restrict__ sB, unsigned long long a0, unsigned long long a1,
    int quad, int l, const short8 (&qf)[2][2], const short4v& ones,
    f32x4 (&acc)[2][4], f32x4 (&acc_l)[2]) {
  a0 >>= (quad * 4);
  a1 >>= (quad * 4);
  const unsigned lo0 = (unsigned)a0, hi0 = (unsigned)(a0 >> 32);
  const unsigned lo1 = (unsigned)a1, hi1 = (unsigned)(a1 >> 32);
  const short* sK = sB;
  const short* sV = sB + 4096;

#pragma unroll
  for (int ntp = 0; ntp < 2; ++ntp) {
    short4v pf[2][2];  // [h][qt]
#pragma unroll
    for (int h = 0; h < 2; ++h) {
      const int nt = ntp * 2 + h;
      f32x4 s0 = {0.f, 0.f, 0.f, 0.f};
      f32x4 s1 = {0.f, 0.f, 0.f, 0.f};
#pragma unroll
      for (int ks = 0; ks < 2; ++ks) {
        short8 kf = *(const short8*)&sK[(nt * 2 + ks) * 512 + l * 8];
        s0 = MFMA32K(kf, qf[0][ks], s0);
        s1 = MFMA32K(kf, qf[1][ks], s1);
      }
      const unsigned w0 = (nt < 2) ? lo0 : hi0;
      const unsigned w1 = (nt < 2) ? lo1 : hi1;
      const int sh = (nt & 1) * 16;
#pragma unroll
      for (int r = 0; r < 4; ++r) {
        float e0 = fast_exp2(s0[r]);
        float e1 = fast_exp2(s1[r]);
        float p0 = ((w0 >> (sh + r)) & 1u) ? e0 : 0.f;
        float p1 = ((w1 >> (sh + r)) & 1u) ? e1 : 0.f;
        pf[h][0][r] = f2bf(p0);
        pf[h][1][r] = f2bf(p1);
      }
      acc_l[0] = MFMA16(ones, pf[h][0], acc_l[0]);
      acc_l[1] = MFMA16(ones, pf[h][1], acc_l[1]);
    }
#pragma unroll
    for (int dt = 0; dt < 4; ++dt) {
      short8 vv = *(const short8*)&sV[(dt * 2 + ntp) * 512 + l * 8];
      short4v vlo, vhi;
      vlo[0] = vv[0]; vlo[1] = vv[1]; vlo[2] = vv[2]; vlo[3] = vv[3];
      vhi[0] = vv[4]; vhi[1] = vv[5]; vhi[2] = vv[6]; vhi[3] = vv[7];
      acc[0][dt] = MFMA16(vlo, pf[0][0], acc[0][dt]);
      acc[1][dt] = MFMA16(vlo, pf[0][1], acc[1][dt]);
      acc[0][dt] = MFMA16(vhi, pf[1][0], acc[0][dt]);
      acc[1][dt] = MFMA16(vhi, pf[1][1], acc[1][dt]);
    }
  }
}

// ---------- main: 4 waves x 32 q-rows; DUAL chunk-streams per wave
// (A: chunks 0-15, B: 16-31), each double-buffered -> 4 independent
// dependency chains per SIMD; streams merged exactly at the end (no running
// max => chunk sums commute). 64 KB LDS/block, 2 blocks/CU.
__global__ __launch_bounds__(256, 2) void gat_flash7(
    const float* __restrict__ x, const short* __restrict__ img,
    const unsigned long long* __restrict__ adjb, float* __restrict__ out) {
  __shared__ short sI[4][8192];  // bufs: A=0/1, B=2/3

  const int tid = threadIdx.x;
  const int w = tid >> 6;
  const int l = tid & 63;
  const int lane16 = l & 15;
  const int quad = l >> 4;
  const int b = blockIdx.y;
  const int qbase = blockIdx.x * 128 + w * 32;

  // ---- Q B-frags, pre-scaled by (1/8)*log2e ----
  const float qs = 0.125f * LOG2E;
  short8 qf[2][2];
#pragma unroll
  for (int qt = 0; qt < 2; ++qt) {
    const float* qp = x + ((size_t)b * NN + qbase + qt * 16 + lane16) * DD;
#pragma unroll
    for (int ks = 0; ks < 2; ++ks) {
      float4 v0 = *(const float4*)(qp + ks * 32 + quad * 8);
      float4 v1 = *(const float4*)(qp + ks * 32 + quad * 8 + 4);
      short8 a;
      a[0] = f2bf(v0.x * qs); a[1] = f2bf(v0.y * qs);
      a[2] = f2bf(v0.z * qs); a[3] = f2bf(v0.w * qs);
      a[4] = f2bf(v1.x * qs); a[5] = f2bf(v1.y * qs);
      a[6] = f2bf(v1.z * qs); a[7] = f2bf(v1.w * qs);
      qf[qt][ks] = a;
    }
  }

  f32x4 accA[2][4], accB[2][4], aclA[2], aclB[2];
#pragma unroll
  for (int qt = 0; qt < 2; ++qt) {
    aclA[qt] = {0.f, 0.f, 0.f, 0.f};
    aclB[qt] = {0.f, 0.f, 0.f, 0.f};
#pragma unroll
    for (int dt = 0; dt < 4; ++dt) {
      accA[qt][dt] = {0.f, 0.f, 0.f, 0.f};
      accB[qt][dt] = {0.f, 0.f, 0.f, 0.f};
    }
  }
  short4v ones;
  ones[0] = 0x3F80; ones[1] = 0x3F80; ones[2] = 0x3F80; ones[3] = 0x3F80;

  const short* img_b = img + (size_t)b * NCH * 16 * 512;
  const unsigned long long* ar0 = adjb + (size_t)(qbase + lane16) * NCH;
  const unsigned long long* ar1 = adjb + (size_t)(qbase + 16 + lane16) * NCH;

  // stage A chunk 0 -> buf0, B chunk 16 -> buf2
#pragma unroll
  for (int i = 0; i < 4; ++i) {
    const int u = i * 4 + w;
    GLOAD_LDS16(img_b + (size_t)u * 512 + l * 8, &sI[0][u * 512]);
    GLOAD_LDS16(img_b + (size_t)16 * 8192 + u * 512 + l * 8, &sI[2][u * 512]);
  }
  __syncthreads();

  for (int c = 0; c < 16; ++c) {
    const int cur = c & 1;
    if (c < 15) {
      const short* pA = img_b + (size_t)(c + 1) * 8192;
      const short* pB = img_b + (size_t)(c + 17) * 8192;
#pragma unroll
      for (int i = 0; i < 4; ++i) {
        const int u = i * 4 + w;
        GLOAD_LDS16(pA + (size_t)u * 512 + l * 8, &sI[cur ^ 1][u * 512]);
        GLOAD_LDS16(pB + (size_t)u * 512 + l * 8, &sI[2 + (cur ^ 1)][u * 512]);
      }
    }

    const unsigned long long a0A = ar0[c], a1A = ar1[c];
    const unsigned long long a0B = ar0[c + 16], a1B = ar1[c + 16];

    chunk_body(sI[cur], a0A, a1A, quad, l, qf, ones, accA, aclA);
    chunk_body(sI[2 + cur], a0B, a1B, quad, l, qf, ones, accB, aclB);

    __syncthreads();
  }

  // ---- merge streams + epilogue ----
#pragma unroll
  for (int qt = 0; qt < 2; ++qt) {
    const float inv = 1.0f / (aclA[qt][0] + aclB[qt][0]);
    float* op =
        out + ((size_t)b * NN + qbase + qt * 16 + lane16) * DD + quad * 4;
#pragma unroll
    for (int dt = 0; dt < 4; ++dt) {
      float4 o;
      o.x = (accA[qt][dt][0] + accB[qt][dt][0]) * inv;
      o.y = (accA[qt][dt][1] + accB[qt][dt][1]) * inv;
      o.z = (accA[qt][dt][2] + accB[qt][dt][2]) * inv;
      o.w = (accA[qt][dt][3] + accB[qt][dt][3]) * inv;
      *(float4*)(op + dt * 16) = o;
    }
  }
}

extern "C" void kernel_launch(void* const* d_in, const int* in_sizes, int n_in,
                              void* d_out, int out_size, void* d_ws,
                              size_t ws_size, hipStream_t stream) {
  const float* x = (const float*)d_in[0];
  const int* adj = (const int*)d_in[1];
  float* out = (float*)d_out;

  short* img = (short*)d_ws;  // 16 MB fragment-major image
  unsigned long long* adjb =
      (unsigned long long*)(img + (size_t)NB * NCH * 16 * 512);  // 512 KB

  prep_img<<<dim3(NCH, NB), 256, 0, stream>>>(x, img);
  prep_adj<<<(NN * NN) / 256, 256, 0, stream>>>(adj, adjb);
  gat_flash7<<<dim3(NN / 128, NB), 256, 0, stream>>>(x, img, adjb, out);
}

// Round 9
// 144.632 us; speedup vs baseline: 1.5776x; 1.0188x over previous
//
#include <hip/hip_runtime.h>
#include <hip/hip_bf16.h>

#define NB 32
#define NN 2048
#define DD 64
#define NCH 32
#define LOG2E 1.44269504088896340736f
#define SQC 0.4246613965f  // sqrt(0.125 * LOG2E)

typedef __attribute__((ext_vector_type(8))) short short8;
typedef __attribute__((ext_vector_type(4))) short short4v;
typedef __attribute__((ext_vector_type(4))) float f32x4;

#define MFMA32K(A, B, C) \
  __builtin_amdgcn_mfma_f32_16x16x32_bf16((A), (B), (C), 0, 0, 0)
#define MFMA16(A, B, C) \
  __builtin_amdgcn_mfma_f32_16x16x16bf16_1k((A), (B), (C), 0, 0, 0)

#define GLOAD_LDS16(gp, lp)                                                   \
  __builtin_amdgcn_global_load_lds(                                          \
      (const __attribute__((address_space(1))) void*)(gp),                   \
      (__attribute__((address_space(3))) void*)(lp), 16, 0, 0)

__device__ __forceinline__ short f2bf(float x) {
  __bf16 h = (__bf16)x;
  return __builtin_bit_cast(short, h);
}

__device__ __forceinline__ float fast_exp2(float x) {
#if __has_builtin(__builtin_amdgcn_exp2f)
  return __builtin_amdgcn_exp2f(x);
#else
  return exp2f(x);
#endif
}

// round-to-nearest bf16 pack of two positive floats: lo -> low short
__device__ __forceinline__ unsigned pack_bf16_rnd(float lo, float hi) {
  unsigned ulo = __builtin_bit_cast(unsigned, lo) + 0x8000u;
  unsigned uhi = __builtin_bit_cast(unsigned, hi) + 0x8000u;
  return __builtin_amdgcn_perm(uhi, ulo, 0x07060302u);
}

// ---------- prep: fragment-major bf16 image; K-units pre-scaled by SQC.
__global__ __launch_bounds__(256) void prep_img(const float* __restrict__ x,
                                                short* __restrict__ img) {
  __shared__ float t[64 * 68];
  const int tid = threadIdx.x;
  const int c = blockIdx.x;
  const int b = blockIdx.y;
  const int r = tid >> 2;
  const int cg = tid & 3;

  const float* src = x + ((size_t)b * NN + c * 64 + r) * DD + cg * 16;
#pragma unroll
  for (int h = 0; h < 4; ++h)
    *(float4*)&t[r * 68 + cg * 16 + h * 4] = ((const float4*)src)[h];
  __syncthreads();

  short* imgc = img + (size_t)(b * NCH + c) * 16 * 512;

  // K units (scaled by SQC)
#pragma unroll
  for (int i = 0; i < 2; ++i) {
    const int kc = tid + i * 256;
    const int u = kc >> 6, l = kc & 63;
    const int nt = u >> 1, ks = u & 1;
    const float* tr = &t[(nt * 16 + (l & 15)) * 68 + ks * 32 + (l >> 4) * 8];
    short8 v;
#pragma unroll
    for (int j = 0; j < 8; ++j) v[j] = f2bf(tr[j] * SQC);
    *(short8*)&imgc[(size_t)u * 512 + l * 8] = v;
  }
  // V units (unscaled, transposed gather)
#pragma unroll
  for (int i = 0; i < 2; ++i) {
    const int vc = tid + i * 256;
    const int u = vc >> 6, l = vc & 63;
    const int dt = u >> 1, ntp = u & 1;
    const int d = dt * 16 + (l & 15);
    const int k0 = ntp * 32 + ((l >> 4) << 2);
    short8 o;
#pragma unroll
    for (int h = 0; h < 2; ++h)
#pragma unroll
      for (int r2 = 0; r2 < 4; ++r2)
        o[h * 4 + r2] = f2bf(t[(k0 + h * 16 + r2) * 68 + d]);
    *(short8*)&imgc[(size_t)(8 + u) * 512 + l * 8] = o;
  }
}

// ---------- prep 2: adj int32 -> bitmask
__global__ __launch_bounds__(256) void prep_adj(const int* __restrict__ adj,
                                                unsigned long long* __restrict__ bits) {
  const int i = blockIdx.x * 256 + threadIdx.x;
  unsigned long long m = __ballot(adj[i] > 0);
  if ((threadIdx.x & 63) == 0) bits[i >> 6] = m;
}

// one chunk's compute
__device__ __forceinline__ void chunk_body(
    const short* __restrict__ sB, unsigned long long a0, unsigned long long a1,
    int quad, int l, const short8 (&qf)[2][2], const short4v& ones,
    f32x4 (&acc)[2][4], f32x4 (&acc_l)[2]) {
  a0 >>= (quad * 4);
  a1 >>= (quad * 4);
  const unsigned lo0 = (unsigned)a0, hi0 = (unsigned)(a0 >> 32);
  const unsigned lo1 = (unsigned)a1, hi1 = (unsigned)(a1 >> 32);
  const short* sK = sB;
  const short* sV = sB + 4096;

#pragma unroll
  for (int ntp = 0; ntp < 2; ++ntp) {
    short4v pf[2][2];  // [h][qt]
#pragma unroll
    for (int h = 0; h < 2; ++h) {
      const int nt = ntp * 2 + h;
      f32x4 s0 = {0.f, 0.f, 0.f, 0.f};
      f32x4 s1 = {0.f, 0.f, 0.f, 0.f};
#pragma unroll
      for (int ks = 0; ks < 2; ++ks) {
        short8 kf = *(const short8*)&sK[(nt * 2 + ks) * 512 + l * 8];
        s0 = MFMA32K(kf, qf[0][ks], s0);
        s1 = MFMA32K(kf, qf[1][ks], s1);
      }
      const unsigned w0 = (nt < 2) ? lo0 : hi0;
      const unsigned w1 = (nt < 2) ? lo1 : hi1;
      const int sh = (nt & 1) * 16;
      float p0[4], p1[4];
#pragma unroll
      for (int r = 0; r < 4; ++r) {
        float e0 = fast_exp2(s0[r]);
        float e1 = fast_exp2(s1[r]);
        p0[r] = ((w0 >> (sh + r)) & 1u) ? e0 : 0.f;
        p1[r] = ((w1 >> (sh + r)) & 1u) ? e1 : 0.f;
      }
      uint2 u0, u1;
      u0.x = pack_bf16_rnd(p0[0], p0[1]);
      u0.y = pack_bf16_rnd(p0[2], p0[3]);
      u1.x = pack_bf16_rnd(p1[0], p1[1]);
      u1.y = pack_bf16_rnd(p1[2], p1[3]);
      pf[h][0] = __builtin_bit_cast(short4v, u0);
      pf[h][1] = __builtin_bit_cast(short4v, u1);
      acc_l[0] = MFMA16(ones, pf[h][0], acc_l[0]);
      acc_l[1] = MFMA16(ones, pf[h][1], acc_l[1]);
    }
#pragma unroll
    for (int dt = 0; dt < 4; ++dt) {
      short8 vv = *(const short8*)&sV[(dt * 2 + ntp) * 512 + l * 8];
      short4v vlo, vhi;
      vlo[0] = vv[0]; vlo[1] = vv[1]; vlo[2] = vv[2]; vlo[3] = vv[3];
      vhi[0] = vv[4]; vhi[1] = vv[5]; vhi[2] = vv[6]; vhi[3] = vv[7];
      acc[0][dt] = MFMA16(vlo, pf[0][0], acc[0][dt]);
      acc[1][dt] = MFMA16(vlo, pf[0][1], acc[1][dt]);
      acc[0][dt] = MFMA16(vhi, pf[1][0], acc[0][dt]);
      acc[1][dt] = MFMA16(vhi, pf[1][1], acc[1][dt]);
    }
  }
}

// ---------- main: dual chunk-streams, XCD-local batches (4 batches/XCD so
// img_b (512 KB) stays L2-resident), Q-frags from the pre-scaled img.
__global__ __launch_bounds__(256, 2) void gat_flash8(
    const short* __restrict__ img, const unsigned long long* __restrict__ adjb,
    float* __restrict__ out) {
  __shared__ short sI[4][8192];  // A bufs 0/1, B bufs 2/3

  const int beta = blockIdx.x;
  const int b = (beta & 7) * 4 + (beta >> 7);  // (beta>>3)>>4
  const int xq = (beta >> 3) & 15;

  const int tid = threadIdx.x;
  const int w = tid >> 6;
  const int l = tid & 63;
  const int lane16 = l & 15;
  const int quad = l >> 4;
  const int qbase = xq * 128 + w * 32;

  const short* img_b = img + (size_t)b * NCH * 16 * 512;

  // Q B-frags straight from img K-units of the q-chunk (scale c = SQC^2 total)
  const int qc = xq * 2 + (w >> 1);
  const int ntq0 = (w & 1) * 2;
  short8 qf[2][2];
#pragma unroll
  for (int qt = 0; qt < 2; ++qt)
#pragma unroll
    for (int ks = 0; ks < 2; ++ks)
      qf[qt][ks] = *(const short8*)&img_b[((size_t)qc * 16 +
                                          (ntq0 + qt) * 2 + ks) * 512 + l * 8];

  f32x4 accA[2][4], accB[2][4], aclA[2], aclB[2];
#pragma unroll
  for (int qt = 0; qt < 2; ++qt) {
    aclA[qt] = {0.f, 0.f, 0.f, 0.f};
    aclB[qt] = {0.f, 0.f, 0.f, 0.f};
#pragma unroll
    for (int dt = 0; dt < 4; ++dt) {
      accA[qt][dt] = {0.f, 0.f, 0.f, 0.f};
      accB[qt][dt] = {0.f, 0.f, 0.f, 0.f};
    }
  }
  short4v ones;
  ones[0] = 0x3F80; ones[1] = 0x3F80; ones[2] = 0x3F80; ones[3] = 0x3F80;

  const unsigned long long* ar0 = adjb + (size_t)(qbase + lane16) * NCH;
  const unsigned long long* ar1 = adjb + (size_t)(qbase + 16 + lane16) * NCH;

#pragma unroll
  for (int i = 0; i < 4; ++i) {
    const int u = i * 4 + w;
    GLOAD_LDS16(img_b + (size_t)u * 512 + l * 8, &sI[0][u * 512]);
    GLOAD_LDS16(img_b + (size_t)16 * 8192 + u * 512 + l * 8, &sI[2][u * 512]);
  }
  __syncthreads();

  for (int c = 0; c < 16; ++c) {
    const int cur = c & 1;
    if (c < 15) {
      const short* pA = img_b + (size_t)(c + 1) * 8192;
      const short* pB = img_b + (size_t)(c + 17) * 8192;
#pragma unroll
      for (int i = 0; i < 4; ++i) {
        const int u = i * 4 + w;
        GLOAD_LDS16(pA + (size_t)u * 512 + l * 8, &sI[cur ^ 1][u * 512]);
        GLOAD_LDS16(pB + (size_t)u * 512 + l * 8, &sI[2 + (cur ^ 1)][u * 512]);
      }
    }

    const unsigned long long a0A = ar0[c], a1A = ar1[c];
    const unsigned long long a0B = ar0[c + 16], a1B = ar1[c + 16];

    chunk_body(sI[cur], a0A, a1A, quad, l, qf, ones, accA, aclA);
    chunk_body(sI[2 + cur], a0B, a1B, quad, l, qf, ones, accB, aclB);

    __syncthreads();
  }

  // ---- merge + epilogue ----
#pragma unroll
  for (int qt = 0; qt < 2; ++qt) {
    const float inv = 1.0f / (aclA[qt][0] + aclB[qt][0]);
    float* op =
        out + ((size_t)b * NN + qbase + qt * 16 + lane16) * DD + quad * 4;
#pragma unroll
    for (int dt = 0; dt < 4; ++dt) {
      float4 o;
      o.x = (accA[qt][dt][0] + accB[qt][dt][0]) * inv;
      o.y = (accA[qt][dt][1] + accB[qt][dt][1]) * inv;
      o.z = (accA[qt][dt][2] + accB[qt][dt][2]) * inv;
      o.w = (accA[qt][dt][3] + accB[qt][dt][3]) * inv;
      *(float4*)(op + dt * 16) = o;
    }
  }
}

extern "C" void kernel_launch(void* const* d_in, const int* in_sizes, int n_in,
                              void* d_out, int out_size, void* d_ws,
                              size_t ws_size, hipStream_t stream) {
  const float* x = (const float*)d_in[0];
  const int* adj = (const int*)d_in[1];
  float* out = (float*)d_out;

  short* img = (short*)d_ws;  // 16 MB fragment-major image
  unsigned long long* adjb =
      (unsigned long long*)(img + (size_t)NB * NCH * 16 * 512);  // 512 KB

  prep_img<<<dim3(NCH, NB), 256, 0, stream>>>(x, img);
  prep_adj<<<(NN * NN) / 256, 256, 0, stream>>>(adj, adjb);
  gat_flash8<<<512, 256, 0, stream>>>(img, adjb, out);
}